// Round 1
// baseline (686.790 us; speedup 1.0000x reference)
//
#include <hip/hip_runtime.h>
#include <math.h>

#define NN 100000
#define NE 3200000
#define INF_ 128
#define D 32
#define H 4
#define HD 8

__device__ __forceinline__ float gelu_f(float x) {
    return 0.5f * x * (1.0f + erff(x * 0.70710678118654752f));
}

// h = gelu(x @ W_in + b_in); block = 256 threads = 8 nodes x 32 cols
__global__ __launch_bounds__(256) void k_in_proj(const float* __restrict__ x,
        const float* __restrict__ W, const float* __restrict__ b,
        float* __restrict__ h) {
    __shared__ float Ws[INF_ * D];     // 16 KB
    __shared__ float xs[8][INF_];      // 4 KB
    for (int i = threadIdx.x; i < INF_ * D; i += 256) Ws[i] = W[i];
    int ln = threadIdx.x >> 5;
    int col = threadIdx.x & 31;
    int node = blockIdx.x * 8 + ln;    // NN/8 = 12500 exact
    const float4* xr = (const float4*)(x + (size_t)node * INF_);
    ((float4*)xs[ln])[col] = xr[col];
    __syncthreads();
    float acc = b[col];
    #pragma unroll 16
    for (int i = 0; i < INF_; ++i) acc = fmaf(xs[ln][i], Ws[i * D + col], acc);
    h[(size_t)node * D + col] = gelu_f(acc);
}

// q,k,v = h @ {Wq,Wk,Wv} + bias; 8 nodes per block
__global__ __launch_bounds__(256) void k_qkv(const float* __restrict__ h,
        const float* __restrict__ Wq, const float* __restrict__ bq,
        const float* __restrict__ Wk, const float* __restrict__ bk,
        const float* __restrict__ Wv, const float* __restrict__ bv,
        float* __restrict__ q, float* __restrict__ k, float* __restrict__ v) {
    __shared__ float Ws[3 * D * D];    // 12 KB
    __shared__ float hs[8][D];
    for (int i = threadIdx.x; i < D * D; i += 256) {
        Ws[i] = Wq[i];
        Ws[D * D + i] = Wk[i];
        Ws[2 * D * D + i] = Wv[i];
    }
    int ln = threadIdx.x >> 5, col = threadIdx.x & 31;
    int node = blockIdx.x * 8 + ln;
    hs[ln][col] = h[(size_t)node * D + col];
    __syncthreads();
    float aq = bq[col], ak = bk[col], av = bv[col];
    #pragma unroll
    for (int i = 0; i < D; ++i) {
        float hv = hs[ln][i];
        aq = fmaf(hv, Ws[i * D + col], aq);
        ak = fmaf(hv, Ws[D * D + i * D + col], ak);
        av = fmaf(hv, Ws[2 * D * D + i * D + col], av);
    }
    size_t o = (size_t)node * D + col;
    q[o] = aq; k[o] = ak; v[o] = av;
}

__global__ void k_zero_i32(int* __restrict__ p, int n) {
    int i = blockIdx.x * blockDim.x + threadIdx.x;
    if (i < n) p[i] = 0;
}

__global__ void k_deg(const int* __restrict__ dst, int* __restrict__ deg) {
    int e = blockIdx.x * blockDim.x + threadIdx.x;
    if (e < NE) atomicAdd(&deg[dst[e]], 1);
}

// block-level exclusive scan (Hillis-Steele inclusive, then subtract self)
__global__ __launch_bounds__(1024) void k_scan1(const int* __restrict__ deg,
        int* __restrict__ rs, int* __restrict__ bsum) {
    __shared__ int s[1024];
    int i = blockIdx.x * 1024 + threadIdx.x;
    int v = (i < NN) ? deg[i] : 0;
    s[threadIdx.x] = v;
    __syncthreads();
    for (int off = 1; off < 1024; off <<= 1) {
        int t = (threadIdx.x >= off) ? s[threadIdx.x - off] : 0;
        __syncthreads();
        s[threadIdx.x] += t;
        __syncthreads();
    }
    if (i < NN) rs[i] = s[threadIdx.x] - v;
    if (threadIdx.x == 1023) bsum[blockIdx.x] = s[1023];
}

__global__ __launch_bounds__(128) void k_scan2(int* __restrict__ bsum, int nb) {
    __shared__ int s[128];
    int v = (threadIdx.x < nb) ? bsum[threadIdx.x] : 0;
    s[threadIdx.x] = v;
    __syncthreads();
    for (int off = 1; off < 128; off <<= 1) {
        int t = (threadIdx.x >= off) ? s[threadIdx.x - off] : 0;
        __syncthreads();
        s[threadIdx.x] += t;
        __syncthreads();
    }
    if (threadIdx.x < nb) bsum[threadIdx.x] = s[threadIdx.x] - v;  // exclusive
}

__global__ __launch_bounds__(1024) void k_scan3(int* __restrict__ rs,
        const int* __restrict__ bsum) {
    int i = blockIdx.x * 1024 + threadIdx.x;
    if (i < NN) rs[i] += bsum[blockIdx.x];
}

__global__ void k_scatter(const int* __restrict__ src, const int* __restrict__ dst,
        const int* __restrict__ rs, int* __restrict__ cnt, int* __restrict__ csr_src) {
    int e = blockIdx.x * blockDim.x + threadIdx.x;
    if (e < NE) {
        int d_ = dst[e];
        int pos = atomicAdd(&cnt[d_], 1);
        csr_src[rs[d_] + pos] = src[e];
    }
}

// fused per-dst attention: one wave per node; lanes = 16 edge-slots x 4 heads
__global__ __launch_bounds__(256) void k_attn(const float* __restrict__ q,
        const float* __restrict__ kk, const float* __restrict__ vv,
        const int* __restrict__ rs, const int* __restrict__ deg,
        const int* __restrict__ csr_src, float* __restrict__ attn) {
    int wid = (blockIdx.x * 256 + threadIdx.x) >> 6;
    int lane = threadIdx.x & 63;
    if (wid >= NN) return;
    int eslot = lane >> 2, head = lane & 3;
    int start = rs[wid], g = deg[wid];
    const float4* kr = (const float4*)(kk + (size_t)wid * D + head * HD);
    float4 k0 = kr[0], k1 = kr[1];
    float m = -INFINITY, l = 0.f;
    float acc[HD];
    #pragma unroll
    for (int i = 0; i < HD; ++i) acc[i] = 0.f;
    for (int base = 0; base < g; base += 16) {
        int idx = base + eslot;
        bool act = idx < g;
        int sn = act ? csr_src[start + idx] : 0;
        float s = -INFINITY;
        if (act) {
            const float4* qr = (const float4*)(q + (size_t)sn * D + head * HD);
            float4 q0 = qr[0], q1 = qr[1];
            s = (q0.x * k0.x + q0.y * k0.y + q0.z * k0.z + q0.w * k0.w
               + q1.x * k1.x + q1.y * k1.y + q1.z * k1.z + q1.w * k1.w)
              * 0.35355339059327376f;
        }
        // per-head chunk max: reduce across the 16 stride-4 lanes of this head
        float cm = s;
        #pragma unroll
        for (int off = 4; off < 64; off <<= 1)
            cm = fmaxf(cm, __shfl_xor(cm, off));
        float nm = fmaxf(m, cm);
        float scale = __expf(m - nm);  // m = -inf first iter -> 0
        m = nm;
        l *= scale;
        #pragma unroll
        for (int i = 0; i < HD; ++i) acc[i] *= scale;
        if (act) {
            float p = __expf(s - nm);
            l += p;
            const float4* vr = (const float4*)(vv + (size_t)sn * D + head * HD);
            float4 v0 = vr[0], v1 = vr[1];
            acc[0] = fmaf(p, v0.x, acc[0]); acc[1] = fmaf(p, v0.y, acc[1]);
            acc[2] = fmaf(p, v0.z, acc[2]); acc[3] = fmaf(p, v0.w, acc[3]);
            acc[4] = fmaf(p, v1.x, acc[4]); acc[5] = fmaf(p, v1.y, acc[5]);
            acc[6] = fmaf(p, v1.z, acc[6]); acc[7] = fmaf(p, v1.w, acc[7]);
        }
    }
    // final reduce of per-lane partials across the 16 edge-slot lanes
    #pragma unroll
    for (int off = 4; off < 64; off <<= 1) {
        l += __shfl_xor(l, off);
        #pragma unroll
        for (int i = 0; i < HD; ++i) acc[i] += __shfl_xor(acc[i], off);
    }
    if (eslot == 0) {
        float inv = (l > 0.f) ? 1.0f / l : 0.f;
        float* outp = attn + (size_t)wid * D + head * HD;
        #pragma unroll
        for (int i = 0; i < HD; ++i) outp[i] = acc[i] * inv;
    }
}

// h += attn @ Wo + bo
__global__ __launch_bounds__(256) void k_oproj(const float* __restrict__ attn,
        const float* __restrict__ Wo, const float* __restrict__ bo,
        float* __restrict__ h) {
    __shared__ float Ws[D * D];
    __shared__ float as[8][D];
    for (int i = threadIdx.x; i < D * D; i += 256) Ws[i] = Wo[i];
    int ln = threadIdx.x >> 5, col = threadIdx.x & 31;
    int node = blockIdx.x * 8 + ln;
    as[ln][col] = attn[(size_t)node * D + col];
    __syncthreads();
    float a = bo[col];
    #pragma unroll
    for (int i = 0; i < D; ++i) a = fmaf(as[ln][i], Ws[i * D + col], a);
    h[(size_t)node * D + col] += a;
}

// h += gelu(h @ W1 + b1) @ W2 + b2
__global__ __launch_bounds__(256) void k_ffn(const float* __restrict__ W1,
        const float* __restrict__ b1, const float* __restrict__ W2,
        const float* __restrict__ b2, float* __restrict__ h) {
    __shared__ float Ws1[D * D], Ws2[D * D];
    __shared__ float hs[8][D], ts[8][D];
    for (int i = threadIdx.x; i < D * D; i += 256) { Ws1[i] = W1[i]; Ws2[i] = W2[i]; }
    int ln = threadIdx.x >> 5, col = threadIdx.x & 31;
    int node = blockIdx.x * 8 + ln;
    float hval = h[(size_t)node * D + col];
    hs[ln][col] = hval;
    __syncthreads();
    float t = b1[col];
    #pragma unroll
    for (int i = 0; i < D; ++i) t = fmaf(hs[ln][i], Ws1[i * D + col], t);
    ts[ln][col] = gelu_f(t);
    __syncthreads();
    float o = b2[col];
    #pragma unroll
    for (int i = 0; i < D; ++i) o = fmaf(ts[ln][i], Ws2[i * D + col], o);
    h[(size_t)node * D + col] = hval + o;
}

// out = h @ W_out + b_out   ([32,2] weights)
__global__ void k_out(const float* __restrict__ h, const float* __restrict__ W,
        const float* __restrict__ b, float* __restrict__ out) {
    int n = blockIdx.x * blockDim.x + threadIdx.x;
    if (n >= NN) return;
    const float4* hr = (const float4*)(h + (size_t)n * D);
    float a0 = b[0], a1 = b[1];
    #pragma unroll
    for (int i = 0; i < 8; ++i) {
        float4 hv = hr[i];
        a0 += hv.x * W[(i * 4 + 0) * 2 + 0] + hv.y * W[(i * 4 + 1) * 2 + 0]
            + hv.z * W[(i * 4 + 2) * 2 + 0] + hv.w * W[(i * 4 + 3) * 2 + 0];
        a1 += hv.x * W[(i * 4 + 0) * 2 + 1] + hv.y * W[(i * 4 + 1) * 2 + 1]
            + hv.z * W[(i * 4 + 2) * 2 + 1] + hv.w * W[(i * 4 + 3) * 2 + 1];
    }
    out[n * 2 + 0] = a0;
    out[n * 2 + 1] = a1;
}

extern "C" void kernel_launch(void* const* d_in, const int* in_sizes, int n_in,
                              void* d_out, int out_size, void* d_ws, size_t ws_size,
                              hipStream_t stream) {
    const float* x     = (const float*)d_in[0];
    const int*   src   = (const int*)d_in[1];
    const int*   dst   = (const int*)d_in[2];
    const float* W_in  = (const float*)d_in[3];
    const float* b_in  = (const float*)d_in[4];
    const float* Wq    = (const float*)d_in[5];
    const float* bq    = (const float*)d_in[6];
    const float* Wk    = (const float*)d_in[7];
    const float* bk    = (const float*)d_in[8];
    const float* Wv    = (const float*)d_in[9];
    const float* bv    = (const float*)d_in[10];
    const float* Wo    = (const float*)d_in[11];
    const float* bo    = (const float*)d_in[12];
    const float* W1    = (const float*)d_in[13];
    const float* b1    = (const float*)d_in[14];
    const float* W2    = (const float*)d_in[15];
    const float* b2    = (const float*)d_in[16];
    const float* W_out = (const float*)d_in[17];
    const float* b_out = (const float*)d_in[18];
    float* out = (float*)d_out;

    char* w = (char*)d_ws;
    size_t off = 0;
    auto alloc = [&](size_t bytes) -> void* {
        void* p = w + off;
        off += (bytes + 255) & ~(size_t)255;
        return p;
    };
    float* h    = (float*)alloc((size_t)NN * D * 4);
    float* q    = (float*)alloc((size_t)NN * D * 4);
    float* kk   = (float*)alloc((size_t)NN * D * 4);
    float* vv   = (float*)alloc((size_t)NN * D * 4);
    float* attn = (float*)alloc((size_t)NN * D * 4);
    int* deg    = (int*)alloc((size_t)NN * 4);
    int* rs     = (int*)alloc((size_t)NN * 4);
    int* cnt    = (int*)alloc((size_t)NN * 4);
    int* bsum   = (int*)alloc(1024);
    int* csr    = (int*)alloc((size_t)NE * 4);
    (void)ws_size; (void)in_sizes; (void)n_in; (void)out_size;

    const int NB_SCAN = (NN + 1023) / 1024;  // 98

    k_in_proj<<<NN / 8, 256, 0, stream>>>(x, W_in, b_in, h);
    k_zero_i32<<<(NN + 255) / 256, 256, 0, stream>>>(deg, NN);
    k_zero_i32<<<(NN + 255) / 256, 256, 0, stream>>>(cnt, NN);
    k_deg<<<NE / 256, 256, 0, stream>>>(dst, deg);
    k_scan1<<<NB_SCAN, 1024, 0, stream>>>(deg, rs, bsum);
    k_scan2<<<1, 128, 0, stream>>>(bsum, NB_SCAN);
    k_scan3<<<NB_SCAN, 1024, 0, stream>>>(rs, bsum);
    k_scatter<<<NE / 256, 256, 0, stream>>>(src, dst, rs, cnt, csr);

    for (int l = 0; l < 2; ++l) {
        k_qkv<<<NN / 8, 256, 0, stream>>>(h, Wq + l * D * D, bq + l * D,
                                          Wk + l * D * D, bk + l * D,
                                          Wv + l * D * D, bv + l * D, q, kk, vv);
        k_attn<<<NN / 4, 256, 0, stream>>>(q, kk, vv, rs, deg, csr, attn);
        k_oproj<<<NN / 8, 256, 0, stream>>>(attn, Wo + l * D * D, bo + l * D, h);
        k_ffn<<<NN / 8, 256, 0, stream>>>(W1 + l * D * D, b1 + l * D,
                                          W2 + l * D * D, b2 + l * D, h);
    }
    k_out<<<(NN + 255) / 256, 256, 0, stream>>>(h, W_out, b_out, out);
}